// Round 10
// baseline (224.075 us; speedup 1.0000x reference)
//
#include <hip/hip_runtime.h>
#include <hip/hip_fp16.h>
#include <math.h>

#define INC 128
#define F1 256
#define HEADS 4
#define NEG_SLOPE 0.2f

typedef _Float16 f16x8 __attribute__((ext_vector_type(8)));
typedef float f32x4 __attribute__((ext_vector_type(4)));

// ---------------- prep: W1T build + degree histogram (fused) ----------------
__global__ __launch_bounds__(256) void prep_kernel(
    const float* __restrict__ W1, _Float16* __restrict__ W1T,
    const int* __restrict__ ei, int* __restrict__ deg,
    int E, int Etot, int nw1t)
{
    int b = blockIdx.x;
    if (b < nw1t) {
        int i = b * 256 + threadIdx.x;   // 32768 elements
        int k = i >> 8;
        int c = i & 255;
        W1T[c * 128 + k] = (_Float16)W1[i];
    } else {
        int e = (b - nw1t) * 256 + threadIdx.x;
        if (e < Etot) {
            int d = (e < E) ? ei[E + e] : (e - E);
            atomicAdd(&deg[d], 1);
        }
    }
}

// ---------------- GEMM1 via MFMA fp16 + scan1 (fused launch) ----------------
__global__ __launch_bounds__(256, 4) void gemm1_scan_kernel(
    const float* __restrict__ x, const _Float16* __restrict__ W1T,
    const float* __restrict__ att_s, const float* __restrict__ att_d,
    __half* __restrict__ h1, float* __restrict__ a_src, float* __restrict__ a_dst,
    int N, int ngemm,
    const int* __restrict__ deg, int* __restrict__ incl, int* __restrict__ bsum)
{
    __shared__ __align__(16) char smem[64 * 264 * 2];
    __shared__ int tmp[256];

    if ((int)blockIdx.x >= ngemm) {
        // ---- scan1 body ----
        int bid = blockIdx.x - ngemm;
        int i = bid * 256 + threadIdx.x;
        int v = (i < N) ? deg[i] : 0;
        tmp[threadIdx.x] = v;
        __syncthreads();
        for (int o = 1; o < 256; o <<= 1) {
            int add = (threadIdx.x >= o) ? tmp[threadIdx.x - o] : 0;
            __syncthreads();
            tmp[threadIdx.x] += add;
            __syncthreads();
        }
        if (i < N) incl[i] = tmp[threadIdx.x];
        if (threadIdx.x == 255) bsum[bid] = tmp[255];
        return;
    }

    _Float16* xh = (_Float16*)smem;       // stride 136
    _Float16* ol = (_Float16*)smem;       // stride 264

    const int tid = threadIdx.x;
    const int wave = tid >> 6;
    const int lane = tid & 63;
    const int q = lane >> 4;
    const int c16 = lane & 15;
    const int row0 = blockIdx.x * 64;

    #pragma unroll
    for (int it = 0; it < 8; ++it) {
        int idx = (tid + it * 256) << 2;
        int r = idx >> 7;
        int c = idx & 127;
        int row = row0 + r;
        float4 v = (row < N) ? *(const float4*)&x[(size_t)row * INC + c]
                             : make_float4(0.f, 0.f, 0.f, 0.f);
        __half2 p0 = __floats2half2_rn(v.x, v.y);
        __half2 p1 = __floats2half2_rn(v.z, v.w);
        uint2 pk;
        pk.x = *(unsigned int*)&p0;
        pk.y = *(unsigned int*)&p1;
        *(uint2*)&xh[r * 136 + c] = pk;
    }
    __syncthreads();

    f16x8 afrag[4];
    #pragma unroll
    for (int kc = 0; kc < 4; ++kc)
        afrag[kc] = *(const f16x8*)&xh[(wave * 16 + c16) * 136 + kc * 32 + q * 8];
    __syncthreads();

    float psS[4][4] = {};
    float psD[4][4] = {};

    #pragma unroll
    for (int nc = 0; nc < 16; ++nc) {
        const int head = nc >> 2;
        const int col = nc * 16 + c16;
        f32x4 acc = {0.f, 0.f, 0.f, 0.f};
        f16x8 b0 = *(const f16x8*)&W1T[(size_t)col * 128 + 0 * 32 + q * 8];
        f16x8 b1 = *(const f16x8*)&W1T[(size_t)col * 128 + 1 * 32 + q * 8];
        f16x8 b2 = *(const f16x8*)&W1T[(size_t)col * 128 + 2 * 32 + q * 8];
        f16x8 b3 = *(const f16x8*)&W1T[(size_t)col * 128 + 3 * 32 + q * 8];
        acc = __builtin_amdgcn_mfma_f32_16x16x32_f16(afrag[0], b0, acc, 0, 0, 0);
        acc = __builtin_amdgcn_mfma_f32_16x16x32_f16(afrag[1], b1, acc, 0, 0, 0);
        acc = __builtin_amdgcn_mfma_f32_16x16x32_f16(afrag[2], b2, acc, 0, 0, 0);
        acc = __builtin_amdgcn_mfma_f32_16x16x32_f16(afrag[3], b3, acc, 0, 0, 0);

        float avs = att_s[col];
        float avd = att_d[col];
        #pragma unroll
        for (int reg = 0; reg < 4; ++reg) {
            float v = acc[reg];
            psS[reg][head] += v * avs;
            psD[reg][head] += v * avd;
            int row = wave * 16 + q * 4 + reg;
            ol[row * 264 + col] = (_Float16)v;
        }
    }

    #pragma unroll
    for (int o = 1; o < 16; o <<= 1) {
        #pragma unroll
        for (int reg = 0; reg < 4; ++reg)
            #pragma unroll
            for (int h = 0; h < 4; ++h) {
                psS[reg][h] += __shfl_xor(psS[reg][h], o);
                psD[reg][h] += __shfl_xor(psD[reg][h], o);
            }
    }
    if (c16 == 0) {
        #pragma unroll
        for (int reg = 0; reg < 4; ++reg) {
            int row = row0 + wave * 16 + q * 4 + reg;
            if (row < N) {
                float4 vs = make_float4(psS[reg][0], psS[reg][1], psS[reg][2], psS[reg][3]);
                float4 vd = make_float4(psD[reg][0], psD[reg][1], psD[reg][2], psD[reg][3]);
                *(float4*)&a_src[row * HEADS] = vs;
                *(float4*)&a_dst[row * HEADS] = vd;
            }
        }
    }

    __syncthreads();
    {
        int r = tid >> 2;
        int cq = (tid & 3) * 64;
        int row = row0 + r;
        if (row < N) {
            #pragma unroll
            for (int j = 0; j < 8; ++j) {
                uint4 v = *(uint4*)&ol[r * 264 + cq + j * 8];
                *(uint4*)&h1[(size_t)row * F1 + cq + j * 8] = v;
            }
        }
    }
}

// ---------------- scan3: off/cursor from incl + local bsum prefix ----------------
__global__ __launch_bounds__(256) void scan3_kernel(
    const int* __restrict__ deg, const int* __restrict__ incl,
    const int* __restrict__ bsum, int* __restrict__ off,
    int* __restrict__ cursor, int N, int Etot, int nb)
{
    __shared__ int tmp[256];
    const int bid = blockIdx.x;
    const int t = threadIdx.x;
    tmp[t] = (t < bid && t < nb) ? bsum[t] : 0;   // nb <= 256
    __syncthreads();
    #pragma unroll
    for (int o = 128; o > 0; o >>= 1) {
        if (t < o) tmp[t] += tmp[t + o];
        __syncthreads();
    }
    int pre = tmp[0];
    int i = bid * 256 + t;
    if (i < N) {
        int ex = incl[i] - deg[i] + pre;
        off[i] = ex;
        cursor[i] = ex;
    } else if (i == N) {
        off[N] = Etot;
    }
}

__global__ void fill_kernel(const int* __restrict__ ei, int* __restrict__ cursor,
                            int* __restrict__ esrc, int E, int Etot)
{
    int e = blockIdx.x * blockDim.x + threadIdx.x;
    if (e >= Etot) return;
    int s, d;
    if (e < E) { s = ei[e]; d = ei[E + e]; }
    else       { s = d = e - E; }
    int pos = atomicAdd(&cursor[d], 1);
    esrc[pos] = s;
}

// ---------------- Layer-1 aggregation + bias + ELU + z = out1 @ W2 ----------------
// One WAVE per node. alpha as half2 in LDS; gather accumulates with __hfma2.
__global__ __launch_bounds__(256) void agg1_kernel(
    const __half* __restrict__ h1, const float* __restrict__ a_src,
    const float* __restrict__ a_dst, const int* __restrict__ off,
    const int* __restrict__ esrc, const float* __restrict__ bias1,
    const float* __restrict__ W2, float* __restrict__ z, int N)
{
    __shared__ unsigned lalh[4][64][4];  // [wave][edge][head] half2{a,a}
    __shared__ int lsrc_s[4][64];

    const int wave = threadIdx.x >> 6;
    const int lane = threadIdx.x & 63;
    const int n = blockIdx.x * 4 + wave;
    if (n >= N) return;

    const int beg = off[n], end = off[n + 1];
    const int deg = end - beg;
    const float4* a_src4 = (const float4*)a_src;
    const uint2* h2 = (const uint2*)h1;
    float4 ad4 = *(const float4*)&a_dst[n * HEADS];
    float ad[4] = {ad4.x, ad4.y, ad4.z, ad4.w};
    const int head = lane >> 4;

    __half2 acc01 = __float2half2_rn(0.f);
    __half2 acc23 = __float2half2_rn(0.f);

    #define GATHER(CNT)                                                          \
    {                                                                            \
        int j = 0;                                                               \
        for (; j + 4 <= (CNT); j += 4) {                                         \
            int s0 = lsrc_s[wave][j + 0];                                        \
            int s1 = lsrc_s[wave][j + 1];                                        \
            int s2 = lsrc_s[wave][j + 2];                                        \
            int s3 = lsrc_s[wave][j + 3];                                        \
            uint2 v0 = h2[(size_t)s0 * 64 + lane];                               \
            uint2 v1 = h2[(size_t)s1 * 64 + lane];                               \
            uint2 v2 = h2[(size_t)s2 * 64 + lane];                               \
            uint2 v3 = h2[(size_t)s3 * 64 + lane];                               \
            unsigned a0 = lalh[wave][j + 0][head];                               \
            unsigned a1 = lalh[wave][j + 1][head];                               \
            unsigned a2 = lalh[wave][j + 2][head];                               \
            unsigned a3 = lalh[wave][j + 3][head];                               \
            acc01 = __hfma2(*(__half2*)&a0, *(__half2*)&v0.x, acc01);            \
            acc23 = __hfma2(*(__half2*)&a0, *(__half2*)&v0.y, acc23);            \
            acc01 = __hfma2(*(__half2*)&a1, *(__half2*)&v1.x, acc01);            \
            acc23 = __hfma2(*(__half2*)&a1, *(__half2*)&v1.y, acc23);            \
            acc01 = __hfma2(*(__half2*)&a2, *(__half2*)&v2.x, acc01);            \
            acc23 = __hfma2(*(__half2*)&a2, *(__half2*)&v2.y, acc23);            \
            acc01 = __hfma2(*(__half2*)&a3, *(__half2*)&v3.x, acc01);            \
            acc23 = __hfma2(*(__half2*)&a3, *(__half2*)&v3.y, acc23);            \
        }                                                                        \
        for (; j < (CNT); ++j) {                                                 \
            int s0 = lsrc_s[wave][j];                                            \
            unsigned a0 = lalh[wave][j][head];                                   \
            uint2 v0 = h2[(size_t)s0 * 64 + lane];                               \
            acc01 = __hfma2(*(__half2*)&a0, *(__half2*)&v0.x, acc01);            \
            acc23 = __hfma2(*(__half2*)&a0, *(__half2*)&v0.y, acc23);            \
        }                                                                        \
    }

    if (deg <= 64) {
        // ---- fast path: single-shot softmax, 4 exps/edge ----
        int i = beg + lane;
        bool valid = i < end;
        int sN = esrc[valid ? i : beg];
        float4 a4 = a_src4[sN];
        float av[4] = {a4.x, a4.y, a4.z, a4.w};
        float ev[4];
        #pragma unroll
        for (int h = 0; h < 4; ++h) {
            float e = av[h] + ad[h];
            e = e > 0.f ? e : NEG_SLOPE * e;
            ev[h] = valid ? e : -1e30f;
        }
        float m[4] = {ev[0], ev[1], ev[2], ev[3]};
        #pragma unroll
        for (int o = 32; o > 0; o >>= 1) {
            #pragma unroll
            for (int h = 0; h < 4; ++h) m[h] = fmaxf(m[h], __shfl_xor(m[h], o));
        }
        float at[4];
        #pragma unroll
        for (int h = 0; h < 4; ++h) at[h] = valid ? __expf(ev[h] - m[h]) : 0.f;
        float s[4] = {at[0], at[1], at[2], at[3]};
        #pragma unroll
        for (int o = 32; o > 0; o >>= 1) {
            #pragma unroll
            for (int h = 0; h < 4; ++h) s[h] += __shfl_xor(s[h], o);
        }
        #pragma unroll
        for (int h = 0; h < 4; ++h) {
            __half2 a2h = __float2half2_rn(at[h] / s[h]);
            lalh[wave][lane][h] = *(unsigned*)&a2h;
        }
        lsrc_s[wave][lane] = sN;

        GATHER(deg);
    } else {
        // ---- slow path: online softmax + chunked gather ----
        float m[4] = {-1e30f, -1e30f, -1e30f, -1e30f};
        float s[4] = {0.f, 0.f, 0.f, 0.f};
        for (int i = beg + lane; i < end; i += 64) {
            int sN = esrc[i];
            float4 a4 = a_src4[sN];
            float av[4] = {a4.x, a4.y, a4.z, a4.w};
            #pragma unroll
            for (int h = 0; h < 4; ++h) {
                float e = av[h] + ad[h];
                e = e > 0.f ? e : NEG_SLOPE * e;
                float nm = fmaxf(m[h], e);
                s[h] = s[h] * __expf(m[h] - nm) + __expf(e - nm);
                m[h] = nm;
            }
        }
        #pragma unroll
        for (int o = 32; o > 0; o >>= 1) {
            #pragma unroll
            for (int h = 0; h < 4; ++h) {
                float om = __shfl_xor(m[h], o);
                float os = __shfl_xor(s[h], o);
                float nm = fmaxf(m[h], om);
                s[h] = s[h] * __expf(m[h] - nm) + os * __expf(om - nm);
                m[h] = nm;
            }
        }
        float inv[4];
        #pragma unroll
        for (int h = 0; h < 4; ++h) inv[h] = 1.f / s[h];

        for (int c0 = beg; c0 < end; c0 += 64) {
            int i = c0 + lane;
            if (i < end) {
                int sN = esrc[i];
                float4 a4 = a_src4[sN];
                float av[4] = {a4.x, a4.y, a4.z, a4.w};
                #pragma unroll
                for (int h = 0; h < 4; ++h) {
                    float e = av[h] + ad[h];
                    e = e > 0.f ? e : NEG_SLOPE * e;
                    __half2 a2h = __float2half2_rn(__expf(e - m[h]) * inv[h]);
                    lalh[wave][lane][h] = *(unsigned*)&a2h;
                }
                lsrc_s[wave][lane] = sN;
            }
            int cend = end - c0;
            if (cend > 64) cend = 64;
            GATHER(cend);
        }
    }
    #undef GATHER

    // bias + ELU + dot with W2
    float acc0 = __half2float(acc01.x);
    float acc1 = __half2float(acc01.y);
    float acc2 = __half2float(acc23.x);
    float acc3 = __half2float(acc23.y);
    float4 b4 = *(const float4*)&bias1[lane << 2];
    float4 w24 = *(const float4*)&W2[lane << 2];
    float o0 = acc0 + b4.x, o1 = acc1 + b4.y, o2 = acc2 + b4.z, o3 = acc3 + b4.w;
    o0 = o0 > 0.f ? o0 : __expf(o0) - 1.f;
    o1 = o1 > 0.f ? o1 : __expf(o1) - 1.f;
    o2 = o2 > 0.f ? o2 : __expf(o2) - 1.f;
    o3 = o3 > 0.f ? o3 : __expf(o3) - 1.f;
    float p = o0 * w24.x + o1 * w24.y + o2 * w24.z + o3 * w24.w;
    #pragma unroll
    for (int o = 32; o > 0; o >>= 1) p += __shfl_xor(p, o);
    if (lane == 0) z[n] = p;
}

// ---------------- Layer-2 aggregation: one wave per node ----------------
__global__ __launch_bounds__(256) void agg2_kernel(
    const float* __restrict__ z, const int* __restrict__ off,
    const int* __restrict__ esrc, const float* __restrict__ att_s2,
    const float* __restrict__ att_d2, const float* __restrict__ bias2,
    float* __restrict__ out, int N)
{
    int wave = threadIdx.x >> 6;
    int lane = threadIdx.x & 63;
    int n = blockIdx.x * 4 + wave;
    if (n >= N) return;
    float as2 = att_s2[0], ad2 = att_d2[0];
    int beg = off[n], end = off[n + 1];
    int deg = end - beg;
    float dstterm = z[n] * ad2;

    if (deg <= 64) {
        int i = beg + lane;
        bool valid = i < end;
        int sN = esrc[valid ? i : beg];
        float zv = z[sN];
        float e = zv * as2 + dstterm;
        e = e > 0.f ? e : NEG_SLOPE * e;
        float ev = valid ? e : -1e30f;
        float m = ev;
        #pragma unroll
        for (int o = 32; o > 0; o >>= 1) m = fmaxf(m, __shfl_xor(m, o));
        float at = valid ? __expf(ev - m) : 0.f;
        float s = at, w = at * zv;
        #pragma unroll
        for (int o = 32; o > 0; o >>= 1) {
            s += __shfl_xor(s, o);
            w += __shfl_xor(w, o);
        }
        if (lane == 0) out[n] = w / s + bias2[0];
    } else {
        float m = -1e30f, s = 0.f, w = 0.f;
        for (int i = beg + lane; i < end; i += 64) {
            int sN = esrc[i];
            float zv = z[sN];
            float e = zv * as2 + dstterm;
            e = e > 0.f ? e : NEG_SLOPE * e;
            float nm = fmaxf(m, e);
            float c0 = __expf(m - nm), c1 = __expf(e - nm);
            s = s * c0 + c1;
            w = w * c0 + c1 * zv;
            m = nm;
        }
        #pragma unroll
        for (int o = 32; o > 0; o >>= 1) {
            float om = __shfl_xor(m, o), os = __shfl_xor(s, o), ow = __shfl_xor(w, o);
            float nm = fmaxf(m, om);
            float c0 = __expf(m - nm), c1 = __expf(om - nm);
            s = s * c0 + os * c1;
            w = w * c0 + ow * c1;
            m = nm;
        }
        if (lane == 0) out[n] = w / s + bias2[0];
    }
}

// ---------------- launch ----------------
extern "C" void kernel_launch(void* const* d_in, const int* in_sizes, int n_in,
                              void* d_out, int out_size, void* d_ws, size_t ws_size,
                              hipStream_t stream)
{
    const float* x        = (const float*)d_in[0];
    const int*   ei       = (const int*)d_in[1];
    const float* W1       = (const float*)d_in[2];
    const float* att_src1 = (const float*)d_in[3];
    const float* att_dst1 = (const float*)d_in[4];
    const float* bias1    = (const float*)d_in[5];
    const float* W2       = (const float*)d_in[6];
    const float* att_src2 = (const float*)d_in[7];
    const float* att_dst2 = (const float*)d_in[8];
    const float* bias2    = (const float*)d_in[9];
    float* out = (float*)d_out;

    int N = in_sizes[0] / INC;
    int E = in_sizes[1] / 2;
    int Etot = E + N;

    char* p = (char*)d_ws;
    auto alloc = [&](size_t bytes) {
        void* r = (void*)p;
        p += (bytes + 255) & ~(size_t)255;
        return r;
    };
    __half* h1      = (__half*)alloc((size_t)N * F1 * 2);
    _Float16* W1T   = (_Float16*)alloc((size_t)INC * F1 * 2);
    float* a_src1 = (float*)alloc((size_t)N * HEADS * 4);
    float* a_dst1 = (float*)alloc((size_t)N * HEADS * 4);
    float* z      = (float*)alloc((size_t)N * 4);
    int* deg    = (int*)alloc((size_t)N * 4);
    int* incl   = (int*)alloc((size_t)N * 4);
    int* off    = (int*)alloc((size_t)(N + 1) * 4);
    int* cursor = (int*)alloc((size_t)N * 4);
    int* bsum   = (int*)alloc(1024);
    int* esrc   = (int*)alloc((size_t)Etot * 4);

    hipMemsetAsync(deg, 0, (size_t)N * 4, stream);

    int nw1t = INC * F1 / 256;              // 128
    int egrid = (Etot + 255) / 256;
    prep_kernel<<<nw1t + egrid, 256, 0, stream>>>(W1, W1T, ei, deg, E, Etot, nw1t);

    int ngemm = (N + 63) / 64;
    int nb = (N + 255) / 256;
    gemm1_scan_kernel<<<ngemm + nb, 256, 0, stream>>>(
        x, W1T, att_src1, att_dst1, h1, a_src1, a_dst1, N, ngemm, deg, incl, bsum);

    int nb1 = (N + 1 + 255) / 256;
    scan3_kernel<<<nb1, 256, 0, stream>>>(deg, incl, bsum, off, cursor, N, Etot, nb);
    fill_kernel<<<egrid, 256, 0, stream>>>(ei, cursor, esrc, E, Etot);

    int ngrid1 = (N + 3) / 4;
    agg1_kernel<<<ngrid1, 256, 0, stream>>>(h1, a_src1, a_dst1, off, esrc, bias1, W2, z, N);

    int ngrid2 = (N + 3) / 4;
    agg2_kernel<<<ngrid2, 256, 0, stream>>>(z, off, esrc, att_src2, att_dst2, bias2, out, N);
}

// Round 11
// 174.975 us; speedup vs baseline: 1.2806x; 1.2806x over previous
//
#include <hip/hip_runtime.h>
#include <hip/hip_fp16.h>
#include <math.h>

#define INC 128
#define F1 256
#define HEADS 4
#define NEG_SLOPE 0.2f

typedef _Float16 f16x8 __attribute__((ext_vector_type(8)));
typedef float f32x4 __attribute__((ext_vector_type(4)));

// ---------------- prep: W1T build + degree histogram w/ rank capture ----------------
__global__ __launch_bounds__(256) void prep_kernel(
    const float* __restrict__ W1, _Float16* __restrict__ W1T,
    const int* __restrict__ ei, int* __restrict__ deg, int* __restrict__ rank,
    int E, int Etot, int nw1t)
{
    int b = blockIdx.x;
    if (b < nw1t) {
        int i = b * 256 + threadIdx.x;   // 32768 elements
        int k = i >> 8;
        int c = i & 255;
        W1T[c * 128 + k] = (_Float16)W1[i];
    } else {
        int e = (b - nw1t) * 256 + threadIdx.x;
        if (e < Etot) {
            int d = (e < E) ? ei[E + e] : (e - E);
            rank[e] = atomicAdd(&deg[d], 1);   // rank within dst bucket, coalesced store
        }
    }
}

// ---------------- scan1: per-256-slice inclusive prefix of deg ----------------
__global__ __launch_bounds__(256) void scan1_kernel(
    const int* __restrict__ deg, int* __restrict__ incl,
    int* __restrict__ bsum, int N)
{
    __shared__ int tmp[256];
    int i = blockIdx.x * 256 + threadIdx.x;
    int v = (i < N) ? deg[i] : 0;
    tmp[threadIdx.x] = v;
    __syncthreads();
    for (int o = 1; o < 256; o <<= 1) {
        int add = (threadIdx.x >= o) ? tmp[threadIdx.x - o] : 0;
        __syncthreads();
        tmp[threadIdx.x] += add;
        __syncthreads();
    }
    if (i < N) incl[i] = tmp[threadIdx.x];
    if (threadIdx.x == 255) bsum[blockIdx.x] = tmp[255];
}

// ---------------- scan3: off from incl + local bsum prefix ----------------
__global__ __launch_bounds__(256) void scan3_kernel(
    const int* __restrict__ deg, const int* __restrict__ incl,
    const int* __restrict__ bsum, int* __restrict__ off,
    int N, int Etot, int nb)
{
    __shared__ int tmp[256];
    const int bid = blockIdx.x;
    const int t = threadIdx.x;
    tmp[t] = (t < bid && t < nb) ? bsum[t] : 0;   // nb <= 256
    __syncthreads();
    #pragma unroll
    for (int o = 128; o > 0; o >>= 1) {
        if (t < o) tmp[t] += tmp[t + o];
        __syncthreads();
    }
    int pre = tmp[0];
    int i = bid * 256 + t;
    if (i < N) {
        off[i] = incl[i] - deg[i] + pre;
    } else if (i == N) {
        off[N] = Etot;
    }
}

// ---------------- fused: GEMM1 (MFMA) || fill (atomic-free scatter) ----------------
__global__ __launch_bounds__(256, 4) void gemm_fill_kernel(
    const float* __restrict__ x, const _Float16* __restrict__ W1T,
    const float* __restrict__ att_s, const float* __restrict__ att_d,
    __half* __restrict__ h1, float* __restrict__ a_src, float* __restrict__ a_dst,
    const int* __restrict__ ei, const int* __restrict__ rank,
    const int* __restrict__ off, int* __restrict__ esrc,
    int N, int E, int Etot, int ngemm)
{
    __shared__ __align__(16) char smem[64 * 264 * 2];

    if ((int)blockIdx.x >= ngemm) {
        // ---- fill body: no atomics, fire-and-forget scatter store ----
        int e = (blockIdx.x - ngemm) * 256 + threadIdx.x;
        if (e < Etot) {
            int s, d;
            if (e < E) { s = ei[e]; d = ei[E + e]; }
            else       { s = d = e - E; }
            esrc[off[d] + rank[e]] = s;
        }
        return;
    }

    _Float16* xh = (_Float16*)smem;       // stride 136
    _Float16* ol = (_Float16*)smem;       // stride 264

    const int tid = threadIdx.x;
    const int wave = tid >> 6;
    const int lane = tid & 63;
    const int q = lane >> 4;
    const int c16 = lane & 15;
    const int row0 = blockIdx.x * 64;

    #pragma unroll
    for (int it = 0; it < 8; ++it) {
        int idx = (tid + it * 256) << 2;
        int r = idx >> 7;
        int c = idx & 127;
        int row = row0 + r;
        float4 v = (row < N) ? *(const float4*)&x[(size_t)row * INC + c]
                             : make_float4(0.f, 0.f, 0.f, 0.f);
        __half2 p0 = __floats2half2_rn(v.x, v.y);
        __half2 p1 = __floats2half2_rn(v.z, v.w);
        uint2 pk;
        pk.x = *(unsigned int*)&p0;
        pk.y = *(unsigned int*)&p1;
        *(uint2*)&xh[r * 136 + c] = pk;
    }
    __syncthreads();

    f16x8 afrag[4];
    #pragma unroll
    for (int kc = 0; kc < 4; ++kc)
        afrag[kc] = *(const f16x8*)&xh[(wave * 16 + c16) * 136 + kc * 32 + q * 8];
    __syncthreads();

    float psS[4][4] = {};
    float psD[4][4] = {};

    #pragma unroll
    for (int nc = 0; nc < 16; ++nc) {
        const int head = nc >> 2;
        const int col = nc * 16 + c16;
        f32x4 acc = {0.f, 0.f, 0.f, 0.f};
        f16x8 b0 = *(const f16x8*)&W1T[(size_t)col * 128 + 0 * 32 + q * 8];
        f16x8 b1 = *(const f16x8*)&W1T[(size_t)col * 128 + 1 * 32 + q * 8];
        f16x8 b2 = *(const f16x8*)&W1T[(size_t)col * 128 + 2 * 32 + q * 8];
        f16x8 b3 = *(const f16x8*)&W1T[(size_t)col * 128 + 3 * 32 + q * 8];
        acc = __builtin_amdgcn_mfma_f32_16x16x32_f16(afrag[0], b0, acc, 0, 0, 0);
        acc = __builtin_amdgcn_mfma_f32_16x16x32_f16(afrag[1], b1, acc, 0, 0, 0);
        acc = __builtin_amdgcn_mfma_f32_16x16x32_f16(afrag[2], b2, acc, 0, 0, 0);
        acc = __builtin_amdgcn_mfma_f32_16x16x32_f16(afrag[3], b3, acc, 0, 0, 0);

        float avs = att_s[col];
        float avd = att_d[col];
        #pragma unroll
        for (int reg = 0; reg < 4; ++reg) {
            float v = acc[reg];
            psS[reg][head] += v * avs;
            psD[reg][head] += v * avd;
            int row = wave * 16 + q * 4 + reg;
            ol[row * 264 + col] = (_Float16)v;
        }
    }

    #pragma unroll
    for (int o = 1; o < 16; o <<= 1) {
        #pragma unroll
        for (int reg = 0; reg < 4; ++reg)
            #pragma unroll
            for (int h = 0; h < 4; ++h) {
                psS[reg][h] += __shfl_xor(psS[reg][h], o);
                psD[reg][h] += __shfl_xor(psD[reg][h], o);
            }
    }
    if (c16 == 0) {
        #pragma unroll
        for (int reg = 0; reg < 4; ++reg) {
            int row = row0 + wave * 16 + q * 4 + reg;
            if (row < N) {
                float4 vs = make_float4(psS[reg][0], psS[reg][1], psS[reg][2], psS[reg][3]);
                float4 vd = make_float4(psD[reg][0], psD[reg][1], psD[reg][2], psD[reg][3]);
                *(float4*)&a_src[row * HEADS] = vs;
                *(float4*)&a_dst[row * HEADS] = vd;
            }
        }
    }

    __syncthreads();
    {
        int r = tid >> 2;
        int cq = (tid & 3) * 64;
        int row = row0 + r;
        if (row < N) {
            #pragma unroll
            for (int j = 0; j < 8; ++j) {
                uint4 v = *(uint4*)&ol[r * 264 + cq + j * 8];
                *(uint4*)&h1[(size_t)row * F1 + cq + j * 8] = v;
            }
        }
    }
}

// ---------------- Layer-1 aggregation + bias + ELU + z = out1 @ W2 ----------------
__global__ __launch_bounds__(256) void agg1_kernel(
    const __half* __restrict__ h1, const float* __restrict__ a_src,
    const float* __restrict__ a_dst, const int* __restrict__ off,
    const int* __restrict__ esrc, const float* __restrict__ bias1,
    const float* __restrict__ W2, float* __restrict__ z, int N)
{
    __shared__ unsigned lalh[4][64][4];  // [wave][edge][head] half2{a,a}
    __shared__ int lsrc_s[4][64];

    const int wave = threadIdx.x >> 6;
    const int lane = threadIdx.x & 63;
    const int n = blockIdx.x * 4 + wave;
    if (n >= N) return;

    const int beg = off[n], end = off[n + 1];
    const int deg = end - beg;
    const float4* a_src4 = (const float4*)a_src;
    const uint2* h2 = (const uint2*)h1;
    float4 ad4 = *(const float4*)&a_dst[n * HEADS];
    float ad[4] = {ad4.x, ad4.y, ad4.z, ad4.w};
    const int head = lane >> 4;

    __half2 acc01 = __float2half2_rn(0.f);
    __half2 acc23 = __float2half2_rn(0.f);

    #define GATHER(CNT)                                                          \
    {                                                                            \
        int j = 0;                                                               \
        for (; j + 4 <= (CNT); j += 4) {                                         \
            int s0 = lsrc_s[wave][j + 0];                                        \
            int s1 = lsrc_s[wave][j + 1];                                        \
            int s2 = lsrc_s[wave][j + 2];                                        \
            int s3 = lsrc_s[wave][j + 3];                                        \
            uint2 v0 = h2[(size_t)s0 * 64 + lane];                               \
            uint2 v1 = h2[(size_t)s1 * 64 + lane];                               \
            uint2 v2 = h2[(size_t)s2 * 64 + lane];                               \
            uint2 v3 = h2[(size_t)s3 * 64 + lane];                               \
            unsigned a0 = lalh[wave][j + 0][head];                               \
            unsigned a1 = lalh[wave][j + 1][head];                               \
            unsigned a2 = lalh[wave][j + 2][head];                               \
            unsigned a3 = lalh[wave][j + 3][head];                               \
            acc01 = __hfma2(*(__half2*)&a0, *(__half2*)&v0.x, acc01);            \
            acc23 = __hfma2(*(__half2*)&a0, *(__half2*)&v0.y, acc23);            \
            acc01 = __hfma2(*(__half2*)&a1, *(__half2*)&v1.x, acc01);            \
            acc23 = __hfma2(*(__half2*)&a1, *(__half2*)&v1.y, acc23);            \
            acc01 = __hfma2(*(__half2*)&a2, *(__half2*)&v2.x, acc01);            \
            acc23 = __hfma2(*(__half2*)&a2, *(__half2*)&v2.y, acc23);            \
            acc01 = __hfma2(*(__half2*)&a3, *(__half2*)&v3.x, acc01);            \
            acc23 = __hfma2(*(__half2*)&a3, *(__half2*)&v3.y, acc23);            \
        }                                                                        \
        for (; j < (CNT); ++j) {                                                 \
            int s0 = lsrc_s[wave][j];                                            \
            unsigned a0 = lalh[wave][j][head];                                   \
            uint2 v0 = h2[(size_t)s0 * 64 + lane];                               \
            acc01 = __hfma2(*(__half2*)&a0, *(__half2*)&v0.x, acc01);            \
            acc23 = __hfma2(*(__half2*)&a0, *(__half2*)&v0.y, acc23);            \
        }                                                                        \
    }

    if (deg <= 64) {
        // ---- fast path: single-shot softmax, 4 exps/edge ----
        int i = beg + lane;
        bool valid = i < end;
        int sN = esrc[valid ? i : beg];
        float4 a4 = a_src4[sN];
        float av[4] = {a4.x, a4.y, a4.z, a4.w};
        float ev[4];
        #pragma unroll
        for (int h = 0; h < 4; ++h) {
            float e = av[h] + ad[h];
            e = e > 0.f ? e : NEG_SLOPE * e;
            ev[h] = valid ? e : -1e30f;
        }
        float m[4] = {ev[0], ev[1], ev[2], ev[3]};
        #pragma unroll
        for (int o = 32; o > 0; o >>= 1) {
            #pragma unroll
            for (int h = 0; h < 4; ++h) m[h] = fmaxf(m[h], __shfl_xor(m[h], o));
        }
        float at[4];
        #pragma unroll
        for (int h = 0; h < 4; ++h) at[h] = valid ? __expf(ev[h] - m[h]) : 0.f;
        float s[4] = {at[0], at[1], at[2], at[3]};
        #pragma unroll
        for (int o = 32; o > 0; o >>= 1) {
            #pragma unroll
            for (int h = 0; h < 4; ++h) s[h] += __shfl_xor(s[h], o);
        }
        #pragma unroll
        for (int h = 0; h < 4; ++h) {
            __half2 a2h = __float2half2_rn(at[h] / s[h]);
            lalh[wave][lane][h] = *(unsigned*)&a2h;
        }
        lsrc_s[wave][lane] = sN;

        GATHER(deg);
    } else {
        // ---- slow path: online softmax + chunked gather ----
        float m[4] = {-1e30f, -1e30f, -1e30f, -1e30f};
        float s[4] = {0.f, 0.f, 0.f, 0.f};
        for (int i = beg + lane; i < end; i += 64) {
            int sN = esrc[i];
            float4 a4 = a_src4[sN];
            float av[4] = {a4.x, a4.y, a4.z, a4.w};
            #pragma unroll
            for (int h = 0; h < 4; ++h) {
                float e = av[h] + ad[h];
                e = e > 0.f ? e : NEG_SLOPE * e;
                float nm = fmaxf(m[h], e);
                s[h] = s[h] * __expf(m[h] - nm) + __expf(e - nm);
                m[h] = nm;
            }
        }
        #pragma unroll
        for (int o = 32; o > 0; o >>= 1) {
            #pragma unroll
            for (int h = 0; h < 4; ++h) {
                float om = __shfl_xor(m[h], o);
                float os = __shfl_xor(s[h], o);
                float nm = fmaxf(m[h], om);
                s[h] = s[h] * __expf(m[h] - nm) + os * __expf(om - nm);
                m[h] = nm;
            }
        }
        float inv[4];
        #pragma unroll
        for (int h = 0; h < 4; ++h) inv[h] = 1.f / s[h];

        for (int c0 = beg; c0 < end; c0 += 64) {
            int i = c0 + lane;
            if (i < end) {
                int sN = esrc[i];
                float4 a4 = a_src4[sN];
                float av[4] = {a4.x, a4.y, a4.z, a4.w};
                #pragma unroll
                for (int h = 0; h < 4; ++h) {
                    float e = av[h] + ad[h];
                    e = e > 0.f ? e : NEG_SLOPE * e;
                    __half2 a2h = __float2half2_rn(__expf(e - m[h]) * inv[h]);
                    lalh[wave][lane][h] = *(unsigned*)&a2h;
                }
                lsrc_s[wave][lane] = sN;
            }
            int cend = end - c0;
            if (cend > 64) cend = 64;
            GATHER(cend);
        }
    }
    #undef GATHER

    // bias + ELU + dot with W2
    float acc0 = __half2float(acc01.x);
    float acc1 = __half2float(acc01.y);
    float acc2 = __half2float(acc23.x);
    float acc3 = __half2float(acc23.y);
    float4 b4 = *(const float4*)&bias1[lane << 2];
    float4 w24 = *(const float4*)&W2[lane << 2];
    float o0 = acc0 + b4.x, o1 = acc1 + b4.y, o2 = acc2 + b4.z, o3 = acc3 + b4.w;
    o0 = o0 > 0.f ? o0 : __expf(o0) - 1.f;
    o1 = o1 > 0.f ? o1 : __expf(o1) - 1.f;
    o2 = o2 > 0.f ? o2 : __expf(o2) - 1.f;
    o3 = o3 > 0.f ? o3 : __expf(o3) - 1.f;
    float p = o0 * w24.x + o1 * w24.y + o2 * w24.z + o3 * w24.w;
    #pragma unroll
    for (int o = 32; o > 0; o >>= 1) p += __shfl_xor(p, o);
    if (lane == 0) z[n] = p;
}

// ---------------- Layer-2 aggregation: one wave per node ----------------
__global__ __launch_bounds__(256) void agg2_kernel(
    const float* __restrict__ z, const int* __restrict__ off,
    const int* __restrict__ esrc, const float* __restrict__ att_s2,
    const float* __restrict__ att_d2, const float* __restrict__ bias2,
    float* __restrict__ out, int N)
{
    int wave = threadIdx.x >> 6;
    int lane = threadIdx.x & 63;
    int n = blockIdx.x * 4 + wave;
    if (n >= N) return;
    float as2 = att_s2[0], ad2 = att_d2[0];
    int beg = off[n], end = off[n + 1];
    int deg = end - beg;
    float dstterm = z[n] * ad2;

    if (deg <= 64) {
        int i = beg + lane;
        bool valid = i < end;
        int sN = esrc[valid ? i : beg];
        float zv = z[sN];
        float e = zv * as2 + dstterm;
        e = e > 0.f ? e : NEG_SLOPE * e;
        float ev = valid ? e : -1e30f;
        float m = ev;
        #pragma unroll
        for (int o = 32; o > 0; o >>= 1) m = fmaxf(m, __shfl_xor(m, o));
        float at = valid ? __expf(ev - m) : 0.f;
        float s = at, w = at * zv;
        #pragma unroll
        for (int o = 32; o > 0; o >>= 1) {
            s += __shfl_xor(s, o);
            w += __shfl_xor(w, o);
        }
        if (lane == 0) out[n] = w / s + bias2[0];
    } else {
        float m = -1e30f, s = 0.f, w = 0.f;
        for (int i = beg + lane; i < end; i += 64) {
            int sN = esrc[i];
            float zv = z[sN];
            float e = zv * as2 + dstterm;
            e = e > 0.f ? e : NEG_SLOPE * e;
            float nm = fmaxf(m, e);
            float c0 = __expf(m - nm), c1 = __expf(e - nm);
            s = s * c0 + c1;
            w = w * c0 + c1 * zv;
            m = nm;
        }
        #pragma unroll
        for (int o = 32; o > 0; o >>= 1) {
            float om = __shfl_xor(m, o), os = __shfl_xor(s, o), ow = __shfl_xor(w, o);
            float nm = fmaxf(m, om);
            float c0 = __expf(m - nm), c1 = __expf(om - nm);
            s = s * c0 + os * c1;
            w = w * c0 + ow * c1;
            m = nm;
        }
        if (lane == 0) out[n] = w / s + bias2[0];
    }
}

// ---------------- launch ----------------
extern "C" void kernel_launch(void* const* d_in, const int* in_sizes, int n_in,
                              void* d_out, int out_size, void* d_ws, size_t ws_size,
                              hipStream_t stream)
{
    const float* x        = (const float*)d_in[0];
    const int*   ei       = (const int*)d_in[1];
    const float* W1       = (const float*)d_in[2];
    const float* att_src1 = (const float*)d_in[3];
    const float* att_dst1 = (const float*)d_in[4];
    const float* bias1    = (const float*)d_in[5];
    const float* W2       = (const float*)d_in[6];
    const float* att_src2 = (const float*)d_in[7];
    const float* att_dst2 = (const float*)d_in[8];
    const float* bias2    = (const float*)d_in[9];
    float* out = (float*)d_out;

    int N = in_sizes[0] / INC;
    int E = in_sizes[1] / 2;
    int Etot = E + N;

    char* p = (char*)d_ws;
    auto alloc = [&](size_t bytes) {
        void* r = (void*)p;
        p += (bytes + 255) & ~(size_t)255;
        return r;
    };
    __half* h1      = (__half*)alloc((size_t)N * F1 * 2);
    _Float16* W1T   = (_Float16*)alloc((size_t)INC * F1 * 2);
    float* a_src1 = (float*)alloc((size_t)N * HEADS * 4);
    float* a_dst1 = (float*)alloc((size_t)N * HEADS * 4);
    float* z      = (float*)alloc((size_t)N * 4);
    int* deg    = (int*)alloc((size_t)N * 4);
    int* incl   = (int*)alloc((size_t)N * 4);
    int* off    = (int*)alloc((size_t)(N + 1) * 4);
    int* rank   = (int*)alloc((size_t)Etot * 4);
    int* bsum   = (int*)alloc(1024);
    int* esrc   = (int*)alloc((size_t)Etot * 4);

    hipMemsetAsync(deg, 0, (size_t)N * 4, stream);

    int nw1t = INC * F1 / 256;              // 128
    int egrid = (Etot + 255) / 256;
    prep_kernel<<<nw1t + egrid, 256, 0, stream>>>(W1, W1T, ei, deg, rank, E, Etot, nw1t);

    int nb = (N + 255) / 256;
    scan1_kernel<<<nb, 256, 0, stream>>>(deg, incl, bsum, N);

    int nb1 = (N + 1 + 255) / 256;
    scan3_kernel<<<nb1, 256, 0, stream>>>(deg, incl, bsum, off, N, Etot, nb);

    int ngemm = (N + 63) / 64;
    gemm_fill_kernel<<<ngemm + egrid, 256, 0, stream>>>(
        x, W1T, att_src1, att_dst1, h1, a_src1, a_dst1,
        ei, rank, off, esrc, N, E, Etot, ngemm);

    int ngrid1 = (N + 3) / 4;
    agg1_kernel<<<ngrid1, 256, 0, stream>>>(h1, a_src1, a_dst1, off, esrc, bias1, W2, z, N);

    int ngrid2 = (N + 3) / 4;
    agg2_kernel<<<ngrid2, 256, 0, stream>>>(z, off, esrc, att_src2, att_dst2, bias2, out, N);
}